// Round 3
// baseline (538.802 us; speedup 1.0000x reference)
//
#include <hip/hip_runtime.h>
#include <hip/hip_bf16.h>
#include <stdint.h>

// Gemma4PatchEmbed round 10: round-9 streaming design with the pipeline tail
// bug fixed (guard was `k16+3 < 47`, must be `< 48`; slice 47 was never
// loaded, slice 45 consumed twice -> absmax 0.369).
// Design: barrier-free, zero-LDS. A fragments for mfma_32x32x16_bf16
// (row=lane&31, k=(lane>>5)*8+j) are 8 CONSECUTIVE floats of one pixel row;
// a wave reads a contiguous 2KB row slice -> load A straight from global,
// convert 2x-1 -> bf16 in-loop (VALU overlaps MFMA), B via non-temporal
// loads, nt stores. One software-pipelined loop per block; no phase lockstep.

typedef __attribute__((ext_vector_type(8))) short bfrag_t;        // MFMA A/B operand
typedef __attribute__((ext_vector_type(16))) float f16acc;         // 32x32 MFMA C/D
typedef __attribute__((ext_vector_type(8))) unsigned short u16x8;

#define V_POS 10240

__device__ __forceinline__ unsigned short f2bf(float f) {
    unsigned int u = __float_as_uint(f);
    u += 0x7fffu + ((u >> 16) & 1u);          // RNE fp32 -> bf16
    return (unsigned short)(u >> 16);
}

// ---------------------------------------------------------------------------
// Kernel 1: pack w_proj into fragment-linear bf16.
// chunk (n32, k16) = 1024 B; lane holds w_proj[n32*32 + (lane&31)]
// [k16*16 + (lane>>5)*8 + j], j<8. 288 blocks x 256 thr.
// ---------------------------------------------------------------------------
__global__ __launch_bounds__(256) void bpack_kernel(
    const float* __restrict__ wp, unsigned short* __restrict__ Bp)
{
    int u     = blockIdx.x * 256 + threadIdx.x;   // 0..73727
    int chunk = u >> 6;                           // 0..1151
    int lane  = u & 63;
    int n32   = chunk / 48;
    int k16   = chunk - n32 * 48;
    int n     = (n32 << 5) + (lane & 31);
    int k     = (k16 << 4) + ((lane >> 5) << 3);
    const float* s = wp + (size_t)n * 768 + k;
    float4 v0 = *(const float4*)s;
    float4 v1 = *(const float4*)(s + 4);
    u16x8 o;
    o[0] = f2bf(v0.x); o[1] = f2bf(v0.y); o[2] = f2bf(v0.z); o[3] = f2bf(v0.w);
    o[4] = f2bf(v1.x); o[5] = f2bf(v1.y); o[6] = f2bf(v1.z); o[7] = f2bf(v1.w);
    *(u16x8*)(Bp + (size_t)chunk * 512 + (lane << 3)) = o;
}

// ---------------------------------------------------------------------------
// Kernel 2: fused patch-extract + GEMM + pos-embed. 512 blocks x 512 threads.
// Block = 32 patch rows (one image patch-row) x 768 N; wave w owns cols
// w*96..w*96+95. Zero LDS, zero barriers.
// ---------------------------------------------------------------------------
__global__ __launch_bounds__(512, 4) void fused_kernel(
    const float* __restrict__ px, const unsigned short* __restrict__ Bp,
    const int* __restrict__ pos_ids, const unsigned int* __restrict__ pad_in,
    const float* __restrict__ pos_table, float* __restrict__ out)
{
    const int tid  = threadIdx.x;
    const int wave = tid >> 6;                // 0..7
    const int lane = tid & 63;
    const int bid  = blockIdx.x;
    const int m0   = bid << 5;                // 32 patch rows per block
    const int img  = bid >> 5;
    const int prow = bid & 31;                // image pixel rows 16*prow .. +16

    // Per-lane A source: 8 consecutive floats at column col8 of pixel row
    // (c, prow*16+py), where (c,py) = (k16>>4, k16&15).
    const int col8 = ((lane & 31) << 4) + ((lane >> 5) << 3);
    const float* pxb = px + (size_t)img * 786432 + (size_t)(prow * 16) * 512 + col8;
    const unsigned short* bbase = Bp + (size_t)(wave * 3) * 48 * 512 + (lane << 3);

    // padding-bool upload-width probe (256 B, in-bounds either way)
    const bool u8mode = __any(pad_in[lane] > 1u);

    f16acc acc[3] = {};

    float4  aCr0, aCr1, aNr0, aNr1;           // raw fp32 A staging (2 buffers)
    bfrag_t bC0, bC1, bC2, bN0, bN1, bN2;     // packed bf16 B fragments

#define LOADA(k, r0, r1) { \
        const float* a_ = pxb + ((k) >> 4) * 262144 + ((k) & 15) * 512; \
        r0 = *(const float4*)a_; r1 = *(const float4*)(a_ + 4); }
#define LOADB(k, r0, r1, r2) { \
        const unsigned short* bk_ = bbase + (size_t)(k) * 512; \
        r0 = __builtin_nontemporal_load((const bfrag_t*)bk_); \
        r1 = __builtin_nontemporal_load((const bfrag_t*)(bk_ + 48 * 512)); \
        r2 = __builtin_nontemporal_load((const bfrag_t*)(bk_ + 96 * 512)); }
#define CVT(r0, r1, dst) { \
        union { bfrag_t v; __hip_bfloat162 h[4]; } u_; \
        u_.h[0] = __float22bfloat162_rn(make_float2(fmaf(2.f, r0.x, -1.f), fmaf(2.f, r0.y, -1.f))); \
        u_.h[1] = __float22bfloat162_rn(make_float2(fmaf(2.f, r0.z, -1.f), fmaf(2.f, r0.w, -1.f))); \
        u_.h[2] = __float22bfloat162_rn(make_float2(fmaf(2.f, r1.x, -1.f), fmaf(2.f, r1.y, -1.f))); \
        u_.h[3] = __float22bfloat162_rn(make_float2(fmaf(2.f, r1.z, -1.f), fmaf(2.f, r1.w, -1.f))); \
        dst = u_.v; }
#define MFMA3(a0, b0, b1, b2)                                                 \
        acc[0] = __builtin_amdgcn_mfma_f32_32x32x16_bf16(a0, b0, acc[0], 0, 0, 0); \
        acc[1] = __builtin_amdgcn_mfma_f32_32x32x16_bf16(a0, b1, acc[1], 0, 0, 0); \
        acc[2] = __builtin_amdgcn_mfma_f32_32x32x16_bf16(a0, b2, acc[2], 0, 0, 0);

    LOADA(0, aCr0, aCr1); LOADB(0, bC0, bC1, bC2);   // prologue: k16 = 0, 1
    LOADA(1, aNr0, aNr1); LOADB(1, bN0, bN1, bN2);

    // steady state: consume buffer, refill with k16+2 (1-iteration lead)
    for (int k16 = 0; k16 < 46; k16 += 2) {
        bfrag_t aC; CVT(aCr0, aCr1, aC);
        MFMA3(aC, bC0, bC1, bC2);
        LOADA(k16 + 2, aCr0, aCr1); LOADB(k16 + 2, bC0, bC1, bC2);
        bfrag_t aN; CVT(aNr0, aNr1, aN);
        MFMA3(aN, bN0, bN1, bN2);
        if (k16 + 3 < 48) { LOADA(k16 + 3, aNr0, aNr1); LOADB(k16 + 3, bN0, bN1, bN2); }
    }
    { bfrag_t aC; CVT(aCr0, aCr1, aC); MFMA3(aC, bC0, bC1, bC2); }  // k16 = 46
    { bfrag_t aN; CVT(aNr0, aNr1, aN); MFMA3(aN, bN0, bN1, bN2); }  // k16 = 47
#undef LOADA
#undef LOADB
#undef CVT
#undef MFMA3

    // ---- epilogue: 32x32 C/D layout col=lane&31, row=(r&3)+8*(r>>2)+4*(lane>>5)
    const unsigned char* pad8 = (const unsigned char*)pad_in;
    const int cl  = lane & 31;
    const int h4  = (lane >> 5) << 2;
#pragma unroll
    for (int r = 0; r < 16; ++r) {
        int row = (r & 3) + ((r >> 2) << 3) + h4;
        int gm  = m0 + row;
        int xid = pos_ids[2 * gm];
        int yid = pos_ids[2 * gm + 1];
        xid = xid < 0 ? 0 : xid;
        yid = yid < 0 ? 0 : yid;
        bool p = u8mode ? (pad8[gm] != 0) : (pad_in[gm] != 0u);
        const float* t0 = pos_table + (size_t)xid * 768;
        const float* t1 = pos_table + (size_t)(V_POS + yid) * 768;
        float* orow = out + (size_t)gm * 768;
#pragma unroll
        for (int nt = 0; nt < 3; ++nt) {
            int col = wave * 96 + (nt << 5) + cl;
            float pos = p ? 0.f : (t0[col] + t1[col]);
            __builtin_nontemporal_store(acc[nt][r] + pos, &orow[col]);
        }
    }
}

extern "C" void kernel_launch(void* const* d_in, const int* in_sizes, int n_in,
                              void* d_out, int out_size, void* d_ws, size_t ws_size,
                              hipStream_t stream) {
    const float*        px  = (const float*)d_in[0];        // (16,3,512,512)
    const float*        wp  = (const float*)d_in[1];        // (768,768)
    const float*        pt  = (const float*)d_in[2];        // (2,10240,768)
    const int*          pid = (const int*)d_in[3];          // (16,1024,2)
    const unsigned int* pad = (const unsigned int*)d_in[4]; // (16,1024) bool

    unsigned short* Bp = (unsigned short*)d_ws;             // 1.18 MB packed bf16

    bpack_kernel<<<288, 256, 0, stream>>>(wp, Bp);
    fused_kernel<<<512, 512, 0, stream>>>(px, Bp, pid, pad, pt, (float*)d_out);
}

// Round 4
// 420.897 us; speedup vs baseline: 1.2801x; 1.2801x over previous
//
#include <hip/hip_runtime.h>
#include <hip/hip_bf16.h>
#include <stdint.h>

// Gemma4PatchEmbed round 11: round-10 streaming design with ALL non-temporal
// hints removed. r10 counters: WRITE_SIZE 49MB -> 753MB (nt 4B stores bypass
// L2 write-combining -> 64B sector per store = 15x amplification), FETCH
// 30 -> 133MB (nt B loads defeat L2 retention of the 1.18MB packed-B hot
// set). Plain loads/stores restore L2 merging and caching.
// Design (unchanged): barrier-free, zero-LDS. A fragments for
// mfma_32x32x16_bf16 (row=lane&31, k=(lane>>5)*8+j) are 8 CONSECUTIVE floats
// of one pixel row; a wave reads a contiguous 2KB row slice -> load A straight
// from global, convert 2x-1 -> bf16 in-loop (VALU overlaps MFMA). One
// software-pipelined loop per block; no phase lockstep, no barriers.

typedef __attribute__((ext_vector_type(8))) short bfrag_t;        // MFMA A/B operand
typedef __attribute__((ext_vector_type(16))) float f16acc;         // 32x32 MFMA C/D
typedef __attribute__((ext_vector_type(8))) unsigned short u16x8;

#define V_POS 10240

__device__ __forceinline__ unsigned short f2bf(float f) {
    unsigned int u = __float_as_uint(f);
    u += 0x7fffu + ((u >> 16) & 1u);          // RNE fp32 -> bf16
    return (unsigned short)(u >> 16);
}

// ---------------------------------------------------------------------------
// Kernel 1: pack w_proj into fragment-linear bf16.
// chunk (n32, k16) = 1024 B; lane holds w_proj[n32*32 + (lane&31)]
// [k16*16 + (lane>>5)*8 + j], j<8. 288 blocks x 256 thr.
// ---------------------------------------------------------------------------
__global__ __launch_bounds__(256) void bpack_kernel(
    const float* __restrict__ wp, unsigned short* __restrict__ Bp)
{
    int u     = blockIdx.x * 256 + threadIdx.x;   // 0..73727
    int chunk = u >> 6;                           // 0..1151
    int lane  = u & 63;
    int n32   = chunk / 48;
    int k16   = chunk - n32 * 48;
    int n     = (n32 << 5) + (lane & 31);
    int k     = (k16 << 4) + ((lane >> 5) << 3);
    const float* s = wp + (size_t)n * 768 + k;
    float4 v0 = *(const float4*)s;
    float4 v1 = *(const float4*)(s + 4);
    u16x8 o;
    o[0] = f2bf(v0.x); o[1] = f2bf(v0.y); o[2] = f2bf(v0.z); o[3] = f2bf(v0.w);
    o[4] = f2bf(v1.x); o[5] = f2bf(v1.y); o[6] = f2bf(v1.z); o[7] = f2bf(v1.w);
    *(u16x8*)(Bp + (size_t)chunk * 512 + (lane << 3)) = o;
}

// ---------------------------------------------------------------------------
// Kernel 2: fused patch-extract + GEMM + pos-embed. 512 blocks x 512 threads.
// Block = 32 patch rows (one image patch-row) x 768 N; wave w owns cols
// w*96..w*96+95. Zero LDS, zero barriers.
// ---------------------------------------------------------------------------
__global__ __launch_bounds__(512, 4) void fused_kernel(
    const float* __restrict__ px, const unsigned short* __restrict__ Bp,
    const int* __restrict__ pos_ids, const unsigned int* __restrict__ pad_in,
    const float* __restrict__ pos_table, float* __restrict__ out)
{
    const int tid  = threadIdx.x;
    const int wave = tid >> 6;                // 0..7
    const int lane = tid & 63;
    const int bid  = blockIdx.x;
    const int m0   = bid << 5;                // 32 patch rows per block
    const int img  = bid >> 5;
    const int prow = bid & 31;                // image pixel rows 16*prow .. +16

    // Per-lane A source: 8 consecutive floats at column col8 of pixel row
    // (c, prow*16+py), where (c,py) = (k16>>4, k16&15).
    const int col8 = ((lane & 31) << 4) + ((lane >> 5) << 3);
    const float* pxb = px + (size_t)img * 786432 + (size_t)(prow * 16) * 512 + col8;
    const unsigned short* bbase = Bp + (size_t)(wave * 3) * 48 * 512 + (lane << 3);

    // padding-bool upload-width probe (256 B, in-bounds either way)
    const bool u8mode = __any(pad_in[lane] > 1u);

    f16acc acc[3] = {};

    float4  aCr0, aCr1, aNr0, aNr1;           // raw fp32 A staging (2 buffers)
    bfrag_t bC0, bC1, bC2, bN0, bN1, bN2;     // packed bf16 B fragments

#define LOADA(k, r0, r1) { \
        const float* a_ = pxb + ((k) >> 4) * 262144 + ((k) & 15) * 512; \
        r0 = *(const float4*)a_; r1 = *(const float4*)(a_ + 4); }
#define LOADB(k, r0, r1, r2) { \
        const unsigned short* bk_ = bbase + (size_t)(k) * 512; \
        r0 = *(const bfrag_t*)bk_; \
        r1 = *(const bfrag_t*)(bk_ + 48 * 512); \
        r2 = *(const bfrag_t*)(bk_ + 96 * 512); }
#define CVT(r0, r1, dst) { \
        union { bfrag_t v; __hip_bfloat162 h[4]; } u_; \
        u_.h[0] = __float22bfloat162_rn(make_float2(fmaf(2.f, r0.x, -1.f), fmaf(2.f, r0.y, -1.f))); \
        u_.h[1] = __float22bfloat162_rn(make_float2(fmaf(2.f, r0.z, -1.f), fmaf(2.f, r0.w, -1.f))); \
        u_.h[2] = __float22bfloat162_rn(make_float2(fmaf(2.f, r1.x, -1.f), fmaf(2.f, r1.y, -1.f))); \
        u_.h[3] = __float22bfloat162_rn(make_float2(fmaf(2.f, r1.z, -1.f), fmaf(2.f, r1.w, -1.f))); \
        dst = u_.v; }
#define MFMA3(a0, b0, b1, b2)                                                 \
        acc[0] = __builtin_amdgcn_mfma_f32_32x32x16_bf16(a0, b0, acc[0], 0, 0, 0); \
        acc[1] = __builtin_amdgcn_mfma_f32_32x32x16_bf16(a0, b1, acc[1], 0, 0, 0); \
        acc[2] = __builtin_amdgcn_mfma_f32_32x32x16_bf16(a0, b2, acc[2], 0, 0, 0);

    LOADA(0, aCr0, aCr1); LOADB(0, bC0, bC1, bC2);   // prologue: k16 = 0, 1
    LOADA(1, aNr0, aNr1); LOADB(1, bN0, bN1, bN2);

    // steady state: consume buffer, refill with k16+2 (1-iteration lead)
    for (int k16 = 0; k16 < 46; k16 += 2) {
        bfrag_t aC; CVT(aCr0, aCr1, aC);
        MFMA3(aC, bC0, bC1, bC2);
        LOADA(k16 + 2, aCr0, aCr1); LOADB(k16 + 2, bC0, bC1, bC2);
        bfrag_t aN; CVT(aNr0, aNr1, aN);
        MFMA3(aN, bN0, bN1, bN2);
        if (k16 + 3 < 48) { LOADA(k16 + 3, aNr0, aNr1); LOADB(k16 + 3, bN0, bN1, bN2); }
    }
    { bfrag_t aC; CVT(aCr0, aCr1, aC); MFMA3(aC, bC0, bC1, bC2); }  // k16 = 46
    { bfrag_t aN; CVT(aNr0, aNr1, aN); MFMA3(aN, bN0, bN1, bN2); }  // k16 = 47
#undef LOADA
#undef LOADB
#undef CVT
#undef MFMA3

    // ---- epilogue: 32x32 C/D layout col=lane&31, row=(r&3)+8*(r>>2)+4*(lane>>5)
    const unsigned char* pad8 = (const unsigned char*)pad_in;
    const int cl  = lane & 31;
    const int h4  = (lane >> 5) << 2;
#pragma unroll
    for (int r = 0; r < 16; ++r) {
        int row = (r & 3) + ((r >> 2) << 3) + h4;
        int gm  = m0 + row;
        int xid = pos_ids[2 * gm];
        int yid = pos_ids[2 * gm + 1];
        xid = xid < 0 ? 0 : xid;
        yid = yid < 0 ? 0 : yid;
        bool p = u8mode ? (pad8[gm] != 0) : (pad_in[gm] != 0u);
        const float* t0 = pos_table + (size_t)xid * 768;
        const float* t1 = pos_table + (size_t)(V_POS + yid) * 768;
        float* orow = out + (size_t)gm * 768;
#pragma unroll
        for (int nt = 0; nt < 3; ++nt) {
            int col = wave * 96 + (nt << 5) + cl;
            float pos = p ? 0.f : (t0[col] + t1[col]);
            orow[col] = acc[nt][r] + pos;
        }
    }
}

extern "C" void kernel_launch(void* const* d_in, const int* in_sizes, int n_in,
                              void* d_out, int out_size, void* d_ws, size_t ws_size,
                              hipStream_t stream) {
    const float*        px  = (const float*)d_in[0];        // (16,3,512,512)
    const float*        wp  = (const float*)d_in[1];        // (768,768)
    const float*        pt  = (const float*)d_in[2];        // (2,10240,768)
    const int*          pid = (const int*)d_in[3];          // (16,1024,2)
    const unsigned int* pad = (const unsigned int*)d_in[4]; // (16,1024) bool

    unsigned short* Bp = (unsigned short*)d_ws;             // 1.18 MB packed bf16

    bpack_kernel<<<288, 256, 0, stream>>>(wp, Bp);
    fused_kernel<<<512, 512, 0, stream>>>(px, Bp, pid, pad, pt, (float*)d_out);
}

// Round 5
// 187.489 us; speedup vs baseline: 2.8738x; 2.2449x over previous
//
#include <hip/hip_runtime.h>
#include <stdint.h>

// Gemma4PatchEmbed round 12: scratch-proof inner loop.
// r11 evidence: removing nt hints changed nothing (WRITE 740MB, FETCH 131MB
// both times) -> the 15x write amplification is NOT cache-policy; the only
// possible writer is compiler-generated SCRATCH. Suspects: the CVT union
// (bfrag_t + __hip_bfloat162 h[4] -- struct array in a union defeats SROA ->
// private-memory round trip every k16) and float4 (HIP struct) staging regs.
// Fix: pure ext_vector types everywhere in the loop, manual RNE bf16 packing
// in integer regs, __builtin_bit_cast instead of unions. No other changes.
// Design (unchanged): barrier-free, zero-LDS. A fragments for
// mfma_32x32x16_bf16 (row=lane&31, k=(lane>>5)*8+j) are 8 CONSECUTIVE floats
// of one pixel row; a wave reads a contiguous 2KB row slice straight from
// global; 2x-1 + bf16 convert on VALU overlaps MFMA; software-pipelined,
// no barriers, no phase lockstep.

typedef __attribute__((ext_vector_type(8))) short bfrag_t;         // MFMA A/B operand
typedef __attribute__((ext_vector_type(16))) float f16acc;          // 32x32 MFMA C/D
typedef __attribute__((ext_vector_type(8))) unsigned short u16x8;
typedef __attribute__((ext_vector_type(4))) float f32x4;            // native, no ctors
typedef __attribute__((ext_vector_type(4))) unsigned int u32x4;

#define V_POS 10240

__device__ __forceinline__ unsigned short f2bf(float f) {
    unsigned int u = __float_as_uint(f);
    u += 0x7fffu + ((u >> 16) & 1u);          // RNE fp32 -> bf16
    return (unsigned short)(u >> 16);
}

// pack bf16(2x-1), bf16(2y-1) into one dword (lo, hi) -- pure int ops
__device__ __forceinline__ unsigned int pk2(float x, float y) {
    unsigned int ux = __float_as_uint(fmaf(2.f, x, -1.f));
    unsigned int uy = __float_as_uint(fmaf(2.f, y, -1.f));
    ux += 0x7fffu + ((ux >> 16) & 1u);
    uy += 0x7fffu + ((uy >> 16) & 1u);
    return (ux >> 16) | (uy & 0xffff0000u);
}

// ---------------------------------------------------------------------------
// Kernel 1: pack w_proj into fragment-linear bf16.
// chunk (n32, k16) = 1024 B; lane holds w_proj[n32*32 + (lane&31)]
// [k16*16 + (lane>>5)*8 + j], j<8. 288 blocks x 256 thr.
// ---------------------------------------------------------------------------
__global__ __launch_bounds__(256) void bpack_kernel(
    const float* __restrict__ wp, unsigned short* __restrict__ Bp)
{
    int u     = blockIdx.x * 256 + threadIdx.x;   // 0..73727
    int chunk = u >> 6;                           // 0..1151
    int lane  = u & 63;
    int n32   = chunk / 48;
    int k16   = chunk - n32 * 48;
    int n     = (n32 << 5) + (lane & 31);
    int k     = (k16 << 4) + ((lane >> 5) << 3);
    const float* s = wp + (size_t)n * 768 + k;
    f32x4 v0 = *(const f32x4*)s;
    f32x4 v1 = *(const f32x4*)(s + 4);
    u16x8 o;
    o[0] = f2bf(v0[0]); o[1] = f2bf(v0[1]); o[2] = f2bf(v0[2]); o[3] = f2bf(v0[3]);
    o[4] = f2bf(v1[0]); o[5] = f2bf(v1[1]); o[6] = f2bf(v1[2]); o[7] = f2bf(v1[3]);
    *(u16x8*)(Bp + (size_t)chunk * 512 + (lane << 3)) = o;
}

// ---------------------------------------------------------------------------
// Kernel 2: fused patch-extract + GEMM + pos-embed. 512 blocks x 512 threads.
// Block = 32 patch rows (one image patch-row) x 768 N; wave w owns cols
// w*96..w*96+95. Zero LDS, zero barriers.
// ---------------------------------------------------------------------------
__global__ __launch_bounds__(512, 4) void fused_kernel(
    const float* __restrict__ px, const unsigned short* __restrict__ Bp,
    const int* __restrict__ pos_ids, const unsigned int* __restrict__ pad_in,
    const float* __restrict__ pos_table, float* __restrict__ out)
{
    const int tid  = threadIdx.x;
    const int wave = tid >> 6;                // 0..7
    const int lane = tid & 63;
    const int bid  = blockIdx.x;
    const int m0   = bid << 5;                // 32 patch rows per block
    const int img  = bid >> 5;
    const int prow = bid & 31;                // image pixel rows 16*prow .. +16

    // Per-lane A source: 8 consecutive floats at column col8 of pixel row
    // (c, prow*16+py), where (c,py) = (k16>>4, k16&15).
    const int col8 = ((lane & 31) << 4) + ((lane >> 5) << 3);
    const float* pxb = px + (size_t)img * 786432 + (size_t)(prow * 16) * 512 + col8;
    const unsigned short* bbase = Bp + (size_t)(wave * 3) * 48 * 512 + (lane << 3);

    // padding-bool upload-width probe (256 B, in-bounds either way)
    const bool u8mode = __any(pad_in[lane] > 1u);

    f16acc acc[3] = {};

    f32x4   aCr0, aCr1, aNr0, aNr1;           // raw fp32 A staging (2 buffers)
    bfrag_t bC0, bC1, bC2, bN0, bN1, bN2;     // packed bf16 B fragments

#define LOADA(k, r0, r1) { \
        const float* a_ = pxb + ((k) >> 4) * 262144 + ((k) & 15) * 512; \
        r0 = *(const f32x4*)a_; r1 = *(const f32x4*)(a_ + 4); }
#define LOADB(k, r0, r1, r2) { \
        const unsigned short* bk_ = bbase + (size_t)(k) * 512; \
        r0 = *(const bfrag_t*)bk_; \
        r1 = *(const bfrag_t*)(bk_ + 48 * 512); \
        r2 = *(const bfrag_t*)(bk_ + 96 * 512); }
#define CVT(r0, r1, dst) { \
        u32x4 pk_; \
        pk_[0] = pk2(r0[0], r0[1]); pk_[1] = pk2(r0[2], r0[3]); \
        pk_[2] = pk2(r1[0], r1[1]); pk_[3] = pk2(r1[2], r1[3]); \
        dst = __builtin_bit_cast(bfrag_t, pk_); }
#define MFMA3(a0, b0, b1, b2)                                                 \
        acc[0] = __builtin_amdgcn_mfma_f32_32x32x16_bf16(a0, b0, acc[0], 0, 0, 0); \
        acc[1] = __builtin_amdgcn_mfma_f32_32x32x16_bf16(a0, b1, acc[1], 0, 0, 0); \
        acc[2] = __builtin_amdgcn_mfma_f32_32x32x16_bf16(a0, b2, acc[2], 0, 0, 0);

    LOADA(0, aCr0, aCr1); LOADB(0, bC0, bC1, bC2);   // prologue: k16 = 0, 1
    LOADA(1, aNr0, aNr1); LOADB(1, bN0, bN1, bN2);

    // steady state: consume buffer, refill with k16+2 (1-iteration lead)
    for (int k16 = 0; k16 < 46; k16 += 2) {
        bfrag_t aC; CVT(aCr0, aCr1, aC);
        MFMA3(aC, bC0, bC1, bC2);
        LOADA(k16 + 2, aCr0, aCr1); LOADB(k16 + 2, bC0, bC1, bC2);
        bfrag_t aN; CVT(aNr0, aNr1, aN);
        MFMA3(aN, bN0, bN1, bN2);
        if (k16 + 3 < 48) { LOADA(k16 + 3, aNr0, aNr1); LOADB(k16 + 3, bN0, bN1, bN2); }
    }
    { bfrag_t aC; CVT(aCr0, aCr1, aC); MFMA3(aC, bC0, bC1, bC2); }  // k16 = 46
    { bfrag_t aN; CVT(aNr0, aNr1, aN); MFMA3(aN, bN0, bN1, bN2); }  // k16 = 47
#undef LOADA
#undef LOADB
#undef CVT
#undef MFMA3

    // ---- epilogue: 32x32 C/D layout col=lane&31, row=(r&3)+8*(r>>2)+4*(lane>>5)
    const unsigned char* pad8 = (const unsigned char*)pad_in;
    const int cl  = lane & 31;
    const int h4  = (lane >> 5) << 2;
#pragma unroll
    for (int r = 0; r < 16; ++r) {
        int row = (r & 3) + ((r >> 2) << 3) + h4;
        int gm  = m0 + row;
        int xid = pos_ids[2 * gm];
        int yid = pos_ids[2 * gm + 1];
        xid = xid < 0 ? 0 : xid;
        yid = yid < 0 ? 0 : yid;
        bool p = u8mode ? (pad8[gm] != 0) : (pad_in[gm] != 0u);
        const float* t0 = pos_table + (size_t)xid * 768;
        const float* t1 = pos_table + (size_t)(V_POS + yid) * 768;
        float* orow = out + (size_t)gm * 768;
#pragma unroll
        for (int nt = 0; nt < 3; ++nt) {
            int col = wave * 96 + (nt << 5) + cl;
            float pos = p ? 0.f : (t0[col] + t1[col]);
            orow[col] = acc[nt][r] + pos;
        }
    }
}

extern "C" void kernel_launch(void* const* d_in, const int* in_sizes, int n_in,
                              void* d_out, int out_size, void* d_ws, size_t ws_size,
                              hipStream_t stream) {
    const float*        px  = (const float*)d_in[0];        // (16,3,512,512)
    const float*        wp  = (const float*)d_in[1];        // (768,768)
    const float*        pt  = (const float*)d_in[2];        // (2,10240,768)
    const int*          pid = (const int*)d_in[3];          // (16,1024,2)
    const unsigned int* pad = (const unsigned int*)d_in[4]; // (16,1024) bool

    unsigned short* Bp = (unsigned short*)d_ws;             // 1.18 MB packed bf16

    bpack_kernel<<<288, 256, 0, stream>>>(wp, Bp);
    fused_kernel<<<512, 512, 0, stream>>>(px, Bp, pid, pad, pt, (float*)d_out);
}

// Round 6
// 186.929 us; speedup vs baseline: 2.8824x; 1.0030x over previous
//
#include <hip/hip_runtime.h>
#include <stdint.h>

// Gemma4PatchEmbed round 13: depth-3 pipeline + v_cvt_pk_bf16_f32 convert.
// r12 confirmed scratch theory (WRITE 740->49MB) and left a latency-bound
// loop: MfmaUtil 10% (=7.4us, exactly compute floor), VALUBusy 21.6% (16us,
// fat pk2 convert), 68% stall -- 1-slot lead (~200cy) < HBM latency (~900cy).
// Fixes: (1) depth-3 circular buffer with named slots (static regs, no
// arrays/no scratch), consume slot j / refill k+3 -> ~600+cy lead, peeled
// tail so steady loop is guard-free (counted vmcnt, never drains);
// (2) convert via inline-asm v_cvt_pk_bf16_f32 (1 instr per bf16 pair):
// 12 VALU/k16 vs ~44. VGPR ~120 <= 128 cap at (512,4).
// Tripwire: WRITE_SIZE > 49MB again => register spill -> scratch.
// Design otherwise unchanged: barrier-free, zero-LDS; A fragments
// (row=lane&31, k=(lane>>5)*8+j) = 8 consecutive floats of one pixel row,
// loaded straight from global; B fragment-linear bf16 from bpack.

typedef __attribute__((ext_vector_type(8))) short bfrag_t;         // MFMA A/B operand
typedef __attribute__((ext_vector_type(16))) float f16acc;          // 32x32 MFMA C/D
typedef __attribute__((ext_vector_type(8))) unsigned short u16x8;
typedef __attribute__((ext_vector_type(4))) float f32x4;            // native, no ctors
typedef __attribute__((ext_vector_type(4))) unsigned int u32x4;

#define V_POS 10240

__device__ __forceinline__ unsigned short f2bf(float f) {
    unsigned int u = __float_as_uint(f);
    u += 0x7fffu + ((u >> 16) & 1u);          // RNE fp32 -> bf16
    return (unsigned short)(u >> 16);
}

// ---------------------------------------------------------------------------
// Kernel 1: pack w_proj into fragment-linear bf16.
// chunk (n32, k16) = 1024 B; lane holds w_proj[n32*32 + (lane&31)]
// [k16*16 + (lane>>5)*8 + j], j<8. 288 blocks x 256 thr.
// ---------------------------------------------------------------------------
__global__ __launch_bounds__(256) void bpack_kernel(
    const float* __restrict__ wp, unsigned short* __restrict__ Bp)
{
    int u     = blockIdx.x * 256 + threadIdx.x;   // 0..73727
    int chunk = u >> 6;                           // 0..1151
    int lane  = u & 63;
    int n32   = chunk / 48;
    int k16   = chunk - n32 * 48;
    int n     = (n32 << 5) + (lane & 31);
    int k     = (k16 << 4) + ((lane >> 5) << 3);
    const float* s = wp + (size_t)n * 768 + k;
    f32x4 v0 = *(const f32x4*)s;
    f32x4 v1 = *(const f32x4*)(s + 4);
    u16x8 o;
    o[0] = f2bf(v0[0]); o[1] = f2bf(v0[1]); o[2] = f2bf(v0[2]); o[3] = f2bf(v0[3]);
    o[4] = f2bf(v1[0]); o[5] = f2bf(v1[1]); o[6] = f2bf(v1[2]); o[7] = f2bf(v1[3]);
    *(u16x8*)(Bp + (size_t)chunk * 512 + (lane << 3)) = o;
}

// ---------------------------------------------------------------------------
// Kernel 2: fused patch-extract + GEMM + pos-embed. 512 blocks x 512 threads.
// Block = 32 patch rows (one image patch-row) x 768 N; wave w owns cols
// w*96..w*96+95. Zero LDS, zero barriers.
// ---------------------------------------------------------------------------
__global__ __launch_bounds__(512, 4) void fused_kernel(
    const float* __restrict__ px, const unsigned short* __restrict__ Bp,
    const int* __restrict__ pos_ids, const unsigned int* __restrict__ pad_in,
    const float* __restrict__ pos_table, float* __restrict__ out)
{
    const int tid  = threadIdx.x;
    const int wave = tid >> 6;                // 0..7
    const int lane = tid & 63;
    const int bid  = blockIdx.x;
    const int m0   = bid << 5;                // 32 patch rows per block
    const int img  = bid >> 5;
    const int prow = bid & 31;                // image pixel rows 16*prow .. +16

    // Per-lane A source: 8 consecutive floats at column col8 of pixel row
    // (c, prow*16+py), where (c,py) = (k16>>4, k16&15).
    const int col8 = ((lane & 31) << 4) + ((lane >> 5) << 3);
    const float* pxb = px + (size_t)img * 786432 + (size_t)(prow * 16) * 512 + col8;
    const unsigned short* bbase = Bp + (size_t)(wave * 3) * 48 * 512 + (lane << 3);

    // padding-bool upload-width probe (256 B, in-bounds either way)
    const bool u8mode = __any(pad_in[lane] > 1u);

    f16acc acc[3] = {};

    // depth-3 circular pipeline: named slots, all-static register use
    f32x4   a0r0, a0r1, a1r0, a1r1, a2r0, a2r1;   // raw fp32 A staging
    bfrag_t b00, b01, b02, b10, b11, b12, b20, b21, b22;

#define LOADA(k, r0, r1) { \
        const float* a_ = pxb + ((k) >> 4) * 262144 + ((k) & 15) * 512; \
        r0 = *(const f32x4*)a_; r1 = *(const f32x4*)(a_ + 4); }
#define LOADB(k, r0, r1, r2) { \
        const unsigned short* bk_ = bbase + (size_t)(k) * 512; \
        r0 = *(const bfrag_t*)bk_; \
        r1 = *(const bfrag_t*)(bk_ + 48 * 512); \
        r2 = *(const bfrag_t*)(bk_ + 96 * 512); }
#define CVTPK(lo, hi, d) asm("v_cvt_pk_bf16_f32 %0, %1, %2" \
        : "=v"(d) : "v"(lo), "v"(hi))
#define CVT(r0, r1, dst) { \
        unsigned int p0_, p1_, p2_, p3_; \
        CVTPK(fmaf(2.f, r0[0], -1.f), fmaf(2.f, r0[1], -1.f), p0_); \
        CVTPK(fmaf(2.f, r0[2], -1.f), fmaf(2.f, r0[3], -1.f), p1_); \
        CVTPK(fmaf(2.f, r1[0], -1.f), fmaf(2.f, r1[1], -1.f), p2_); \
        CVTPK(fmaf(2.f, r1[2], -1.f), fmaf(2.f, r1[3], -1.f), p3_); \
        u32x4 pk_ = {p0_, p1_, p2_, p3_}; \
        dst = __builtin_bit_cast(bfrag_t, pk_); }
#define MFMA3(a0, b0, b1, b2)                                                 \
        acc[0] = __builtin_amdgcn_mfma_f32_32x32x16_bf16(a0, b0, acc[0], 0, 0, 0); \
        acc[1] = __builtin_amdgcn_mfma_f32_32x32x16_bf16(a0, b1, acc[1], 0, 0, 0); \
        acc[2] = __builtin_amdgcn_mfma_f32_32x32x16_bf16(a0, b2, acc[2], 0, 0, 0);
// one pipeline slot: consume (CVT+MFMA), refill with k-next. A-load issued
// before the MFMAs (long HBM latency), B-load after (L2-resident, short).
#define STEP(kn, ar0, ar1, bb0, bb1, bb2) { \
        bfrag_t a_f; CVT(ar0, ar1, a_f); \
        LOADA(kn, ar0, ar1); \
        MFMA3(a_f, bb0, bb1, bb2); \
        LOADB(kn, bb0, bb1, bb2); }
#define STEPT(ar0, ar1, bb0, bb1, bb2) { \
        bfrag_t a_f; CVT(ar0, ar1, a_f); \
        MFMA3(a_f, bb0, bb1, bb2); }

    LOADA(0, a0r0, a0r1); LOADB(0, b00, b01, b02);   // prologue: k16 = 0,1,2
    LOADA(1, a1r0, a1r1); LOADB(1, b10, b11, b12);
    LOADA(2, a2r0, a2r1); LOADB(2, b20, b21, b22);

    // steady state: 15 iterations, consume k16..k16+2, refill k16+3..k16+5.
    // Last refill is k16=42 -> loads 45,46,47; no guards needed.
    for (int k16 = 0; k16 < 45; k16 += 3) {
        STEP(k16 + 3, a0r0, a0r1, b00, b01, b02);
        STEP(k16 + 4, a1r0, a1r1, b10, b11, b12);
        STEP(k16 + 5, a2r0, a2r1, b20, b21, b22);
    }
    STEPT(a0r0, a0r1, b00, b01, b02);   // k16 = 45
    STEPT(a1r0, a1r1, b10, b11, b12);   // k16 = 46
    STEPT(a2r0, a2r1, b20, b21, b22);   // k16 = 47
#undef LOADA
#undef LOADB
#undef CVTPK
#undef CVT
#undef MFMA3
#undef STEP
#undef STEPT

    // ---- epilogue: 32x32 C/D layout col=lane&31, row=(r&3)+8*(r>>2)+4*(lane>>5)
    const unsigned char* pad8 = (const unsigned char*)pad_in;
    const int cl  = lane & 31;
    const int h4  = (lane >> 5) << 2;
#pragma unroll
    for (int r = 0; r < 16; ++r) {
        int row = (r & 3) + ((r >> 2) << 3) + h4;
        int gm  = m0 + row;
        int xid = pos_ids[2 * gm];
        int yid = pos_ids[2 * gm + 1];
        xid = xid < 0 ? 0 : xid;
        yid = yid < 0 ? 0 : yid;
        bool p = u8mode ? (pad8[gm] != 0) : (pad_in[gm] != 0u);
        const float* t0 = pos_table + (size_t)xid * 768;
        const float* t1 = pos_table + (size_t)(V_POS + yid) * 768;
        float* orow = out + (size_t)gm * 768;
#pragma unroll
        for (int nt = 0; nt < 3; ++nt) {
            int col = wave * 96 + (nt << 5) + cl;
            float pos = p ? 0.f : (t0[col] + t1[col]);
            orow[col] = acc[nt][r] + pos;
        }
    }
}

extern "C" void kernel_launch(void* const* d_in, const int* in_sizes, int n_in,
                              void* d_out, int out_size, void* d_ws, size_t ws_size,
                              hipStream_t stream) {
    const float*        px  = (const float*)d_in[0];        // (16,3,512,512)
    const float*        wp  = (const float*)d_in[1];        // (768,768)
    const float*        pt  = (const float*)d_in[2];        // (2,10240,768)
    const int*          pid = (const int*)d_in[3];          // (16,1024,2)
    const unsigned int* pad = (const unsigned int*)d_in[4]; // (16,1024) bool

    unsigned short* Bp = (unsigned short*)d_ws;             // 1.18 MB packed bf16

    bpack_kernel<<<288, 256, 0, stream>>>(wp, Bp);
    fused_kernel<<<512, 512, 0, stream>>>(px, Bp, pid, pad, pt, (float*)d_out);
}